// Round 1
// baseline (347.263 us; speedup 1.0000x reference)
//
#include <hip/hip_runtime.h>
#include <stdint.h>

#define H 128
#define W 128
#define CIN 64
#define COUT 64
#define NB 8
#define OFFC 18   // 2*K offset channels

typedef __attribute__((ext_vector_type(4))) float f32x4;
typedef __attribute__((ext_vector_type(8))) short bf16x8;

__device__ __forceinline__ unsigned short f2bf(float f) {
    union { float f; unsigned u; } v; v.f = f;
    return (unsigned short)((v.u + 0x7FFFu + ((v.u >> 16) & 1u)) >> 16);
}

// ---- kernel 0: prepack w_conv to bf16, k' = ktap*64 + c ordering
//      wb2[m*576 + k*64 + c] = bf16(w_conv[(m*64 + c)*9 + k])
__global__ __launch_bounds__(256) void prep_w(const float* __restrict__ wc,
                                              unsigned short* __restrict__ wb2) {
    int t = blockIdx.x * 256 + threadIdx.x;
    if (t >= COUT * 576) return;
    int m = t / 576;
    int r = t - m * 576;
    int k = r >> 6;
    int c = r & 63;
    wb2[t] = f2bf(wc[(m * 64 + c) * 9 + k]);
}

// ---- kernel 1: 3x3 offset conv, pad 1. One thread per pixel, all 18 outputs.
__global__ __launch_bounds__(256) void offset_conv(const float* __restrict__ x,
                                                   const float* __restrict__ wo,
                                                   const float* __restrict__ bo,
                                                   float* __restrict__ offs) {
    int t = blockIdx.x * 256 + threadIdx.x;  // pixel id over NB*H*W = 131072
    int w = t & (W - 1);
    int h = (t >> 7) & (H - 1);
    int b = t >> 14;
    float acc[OFFC];
    #pragma unroll
    for (int o = 0; o < OFFC; ++o) acc[o] = bo[o];
    const float* xb = x + (size_t)b * CIN * H * W;
    for (int ci = 0; ci < CIN; ++ci) {
        const float* xc = xb + ci * (H * W);
        float xv[9];
        #pragma unroll
        for (int ky = 0; ky < 3; ++ky) {
            int y = h + ky - 1;
            int yc = min(max(y, 0), H - 1);
            bool yv = (unsigned)y < (unsigned)H;
            #pragma unroll
            for (int kx = 0; kx < 3; ++kx) {
                int xi = w + kx - 1;
                int xci = min(max(xi, 0), W - 1);
                bool v = yv && ((unsigned)xi < (unsigned)W);
                float val = xc[yc * W + xci];
                xv[ky * 3 + kx] = v ? val : 0.f;
            }
        }
        #pragma unroll
        for (int o = 0; o < OFFC; ++o) {
            const float* wr = wo + (o * CIN + ci) * 9;  // wave-uniform -> s_load
            #pragma unroll
            for (int i = 0; i < 9; ++i) acc[o] = fmaf(wr[i], xv[i], acc[o]);
        }
    }
    int base = ((b * OFFC) * H + h) * W + w;
    #pragma unroll
    for (int o = 0; o < OFFC; ++o) offs[base + o * (H * W)] = acc[o];
}

// ---- kernel 2: deformable conv via MFMA.
// Block = 256 thr (4 waves) handles one 64-pixel row strip (b, h, w0..w0+63).
// Wave wv owns n-tile = pixels [w0+16*wv, +16). Each lane samples its own
// B-fragment elements (k' = ktap*64 + c ordering -> one tap per 32-chunk).
__global__ __launch_bounds__(256) void deform_mfma(const float* __restrict__ x,
                                                   const float* __restrict__ offs,
                                                   const unsigned short* __restrict__ wb2,
                                                   const float* __restrict__ bconv,
                                                   float* __restrict__ out) {
    __shared__ unsigned s_aw[576];   // per (k,pix): a00 | dx<<16 | dy<<17
    __shared__ f32x4   s_wgt[576];   // per (k,pix): folded bilinear weights

    int strip = blockIdx.x;          // 0..2047
    int w0 = (strip & 1) << 6;
    int h  = (strip >> 1) & (H - 1);
    int b  = strip >> 8;

    int t = threadIdx.x;
    for (int it = t; it < 576; it += 256) {   // it = k*64 + pix
        int k = it >> 6;
        int pix = it & 63;
        int wp = w0 + pix;
        float dy = offs[((b * OFFC + 2 * k) * H + h) * W + wp];
        float dx = offs[((b * OFFC + 2 * k + 1) * H + h) * W + wp];
        float py = (float)(h + (k / 3) - 1) + dy;
        float px = (float)(wp + (k % 3) - 1) + dx;
        float y0f = floorf(py), x0f = floorf(px);
        float fy = py - y0f, fx = px - x0f;
        float vy0 = (y0f >= 0.f  && y0f <= 127.f) ? 1.f : 0.f;
        float vy1 = (y0f >= -1.f && y0f <= 126.f) ? 1.f : 0.f;
        float vx0 = (x0f >= 0.f  && x0f <= 127.f) ? 1.f : 0.f;
        float vx1 = (x0f >= -1.f && x0f <= 126.f) ? 1.f : 0.f;
        f32x4 wg;
        wg[0] = (1.f - fy) * (1.f - fx) * vy0 * vx0;
        wg[1] = (1.f - fy) * fx         * vy0 * vx1;
        wg[2] = fy * (1.f - fx)         * vy1 * vx0;
        wg[3] = fy * fx                 * vy1 * vx1;
        int y0i = (int)fminf(fmaxf(y0f, 0.f), 127.f);
        int x0i = (int)fminf(fmaxf(x0f, 0.f), 127.f);
        int y1i = (int)fminf(fmaxf(y0f + 1.f, 0.f), 127.f);
        int x1i = (int)fminf(fmaxf(x0f + 1.f, 0.f), 127.f);
        unsigned a00 = (unsigned)(y0i * W + x0i);
        unsigned dxb = (unsigned)(x1i - x0i);   // 0/1
        unsigned dyb = (unsigned)(y1i - y0i);   // 0/1
        s_aw[it] = a00 | (dxb << 16) | (dyb << 17);
        s_wgt[it] = wg;
    }
    __syncthreads();

    int lane = t & 63;
    int wv   = t >> 6;          // wave id = n-tile
    int pcol = lane & 15;       // MFMA col (pixel within n-tile)
    int hq   = lane >> 4;       // lane quarter
    int pix  = (wv << 4) | pcol;

    const float* xb = x + (size_t)b * CIN * H * W;
    f32x4 acc[4] = {};          // 4 m-tiles of 16 co

    #pragma unroll 1
    for (int kk = 0; kk < 18; ++kk) {
        int k = kk >> 1;        // tap constant over the whole 32-chunk
        unsigned aw = s_aw[(k << 6) | pix];
        f32x4 wg   = s_wgt[(k << 6) | pix];
        unsigned a00 = aw & 0xFFFFu;
        unsigned dxb = (aw >> 16) & 1u;
        unsigned a01 = a00 + dxb;
        unsigned a10 = a00 + (((aw >> 17) & 1u) << 7);   // +W if dy
        unsigned a11 = a10 + dxb;
        const float* xc = xb + (((kk & 1) << 5) + (hq << 3)) * (H * W);
        bf16x8 bfrag;
        #pragma unroll
        for (int j = 0; j < 8; ++j) {    // c = (kk&1)*32 + hq*8 + j
            const float* xcj = xc + j * (H * W);
            float v = wg[0] * xcj[a00] + wg[1] * xcj[a01]
                    + wg[2] * xcj[a10] + wg[3] * xcj[a11];
            bfrag[j] = (short)f2bf(v);
        }
        const unsigned short* arow = wb2 + pcol * 576 + (kk << 5) + (hq << 3);
        #pragma unroll
        for (int m = 0; m < 4; ++m) {
            bf16x8 af = *(const bf16x8*)(arow + m * 16 * 576);
            acc[m] = __builtin_amdgcn_mfma_f32_16x16x32_bf16(af, bfrag, acc[m], 0, 0, 0);
        }
    }

    int ww = w0 + (wv << 4) + pcol;
    #pragma unroll
    for (int m = 0; m < 4; ++m) {
        #pragma unroll
        for (int r = 0; r < 4; ++r) {
            int co = (m << 4) + (hq << 2) + r;   // D: row=(lane>>4)*4+r, col=lane&15
            out[(((size_t)b * COUT + co) * H + h) * W + ww] = acc[m][r] + bconv[co];
        }
    }
}

extern "C" void kernel_launch(void* const* d_in, const int* in_sizes, int n_in,
                              void* d_out, int out_size, void* d_ws, size_t ws_size,
                              hipStream_t stream) {
    const float* x  = (const float*)d_in[0];
    const float* wo = (const float*)d_in[1];
    const float* bo = (const float*)d_in[2];
    const float* wc = (const float*)d_in[3];
    const float* bc = (const float*)d_in[4];
    float* out = (float*)d_out;

    float* offs = (float*)d_ws;                                   // 8*18*128*128 f32 = 9.44 MB
    unsigned short* wb2 = (unsigned short*)((char*)d_ws + (size_t)NB * OFFC * H * W * 4);  // 73.7 KB

    prep_w<<<(COUT * 576 + 255) / 256, 256, 0, stream>>>(wc, wb2);
    offset_conv<<<(NB * H * W) / 256, 256, 0, stream>>>(x, wo, bo, offs);
    deform_mfma<<<NB * H * 2, 256, 0, stream>>>(x, offs, wb2, bc, out);
}

// Round 2
// 208.114 us; speedup vs baseline: 1.6686x; 1.6686x over previous
//
#include <hip/hip_runtime.h>
#include <stdint.h>

#define H 128
#define W 128
#define CIN 64
#define COUT 64
#define NB 8
#define OFFC 18   // 2*K offset channels

typedef __attribute__((ext_vector_type(4))) float f32x4;
typedef __attribute__((ext_vector_type(2))) _Float16 f16x2;
typedef __attribute__((ext_vector_type(8))) _Float16 f16x8;
typedef __attribute__((ext_vector_type(4))) unsigned int u32x4;

__device__ __forceinline__ f16x2 bch2(unsigned u) { return __builtin_bit_cast(f16x2, u); }
__device__ __forceinline__ unsigned bcu(f16x2 v) { return __builtin_bit_cast(unsigned, v); }

// ---- kernel 0: x NCHW f32 -> NHWC f16 (xt[b][h][w][c]) via LDS tile transpose
__global__ __launch_bounds__(256) void x_to_nhwc(const float* __restrict__ x,
                                                 _Float16* __restrict__ xt) {
    __shared__ _Float16 tile[W][68];   // [w][c], row 136 B (8-aligned), pad kills worst conflicts
    int bh = blockIdx.x;               // b*128 + h
    int h = bh & (H - 1), b = bh >> 7;
    int t = threadIdx.x;
    #pragma unroll
    for (int i = 0; i < 8; ++i) {
        int idx = i * 256 + t;         // 2048 items: c 0..63 x w4 0..124
        int c = idx >> 5;
        int w4 = (idx & 31) << 2;
        f32x4 v = *(const f32x4*)(x + (((size_t)(b * CIN + c) * H + h) * W + w4));
        #pragma unroll
        for (int j = 0; j < 4; ++j) tile[w4 + j][c] = (_Float16)v[j];
    }
    __syncthreads();
    _Float16* dst = xt + (size_t)bh * W * CIN;
    #pragma unroll
    for (int i = 0; i < 8; ++i) {
        int idx = i * 256 + t;         // 2048 items: w 0..127 x c4 0..60
        int w = idx >> 4;
        int c4 = (idx & 15) << 2;
        *(uint2*)(dst + (size_t)w * CIN + c4) = *(const uint2*)&tile[w][c4];
    }
}

// ---- kernel 1: prepack weights to f16, k' = ktap*64 + c ordering
//  wao[m*576 + k*64 + c] (m 0..31, zero-pad m>=18), wac[m*576 + k*64 + c] (m 0..63)
__global__ __launch_bounds__(256) void prep_w(const float* __restrict__ wo,
                                              const float* __restrict__ wc,
                                              _Float16* __restrict__ wao,
                                              _Float16* __restrict__ wac) {
    int t = blockIdx.x * 256 + threadIdx.x;
    if (t < 32 * 576) {
        int m = t / 576, r = t - m * 576, k = r >> 6, c = r & 63;
        wao[t] = (m < 18) ? (_Float16)wo[(m * 64 + c) * 9 + k] : (_Float16)0.f;
    } else if (t < 96 * 576) {
        int t2 = t - 32 * 576;
        int m = t2 / 576, r = t2 - m * 576, k = r >> 6, c = r & 63;
        wac[t2] = (_Float16)wc[(m * 64 + c) * 9 + k];
    }
}

// ---- kernel 2: fused offset-conv (MFMA) + coord setup + deformable conv (MFMA)
// Block = 256 thr (4 waves) owns one 64-pixel row strip (b, h, w0..w0+63).
__global__ __launch_bounds__(256, 4) void deform_fused(const _Float16* __restrict__ xt,
                                                       const _Float16* __restrict__ wao,
                                                       const _Float16* __restrict__ wac,
                                                       const float* __restrict__ bo,
                                                       const float* __restrict__ bconv,
                                                       float* __restrict__ out) {
    __shared__ float    s_off[64][OFFC];  // per-pixel 18 offset channels
    __shared__ unsigned s_aw[576];        // per (k,pix): a00 | dx<<16 | dy<<17
    __shared__ u32x4    s_wgt[576];       // per (k,pix): 4 dup-packed f16 bilinear weights

    int strip = blockIdx.x;               // 0..2047
    int w0 = (strip & 1) << 6;
    int h  = (strip >> 1) & (H - 1);
    int b  = strip >> 8;

    int t = threadIdx.x;
    int lane = t & 63;
    int wv   = t >> 6;
    int pcol = lane & 15;
    int hq   = lane >> 4;
    int pix  = (wv << 4) | pcol;
    int wp   = w0 + pix;

    const _Float16* xb = xt + (size_t)b * H * W * CIN;

    // ---------- phase A: offset conv via MFMA (fixed integer taps) ----------
    {
        f32x4 ao0 = {}, ao1 = {};
        #pragma unroll 2
        for (int kk = 0; kk < 18; ++kk) {
            int k = kk >> 1;
            int yy = h + (k / 3) - 1;
            int xx = wp + (k % 3) - 1;
            bool valid = ((unsigned)yy < (unsigned)H) && ((unsigned)xx < (unsigned)W);
            int yc = min(max(yy, 0), H - 1);
            int xc = min(max(xx, 0), W - 1);
            int c0 = ((kk & 1) << 5) + (hq << 3);
            u32x4 d = *(const u32x4*)(xb + ((size_t)(yc * W + xc) * CIN + c0));
            u32x4 zero = {};
            if (!valid) d = zero;
            f16x8 bfrag = __builtin_bit_cast(f16x8, d);
            const _Float16* arow = wao + pcol * 576 + (kk << 5) + (hq << 3);
            f16x8 a0 = *(const f16x8*)(arow);
            f16x8 a1 = *(const f16x8*)(arow + 16 * 576);
            ao0 = __builtin_amdgcn_mfma_f32_16x16x32_f16(a0, bfrag, ao0, 0, 0, 0);
            ao1 = __builtin_amdgcn_mfma_f32_16x16x32_f16(a1, bfrag, ao1, 0, 0, 0);
        }
        #pragma unroll
        for (int r = 0; r < 4; ++r) s_off[pix][hq * 4 + r] = ao0[r] + bo[hq * 4 + r];
        if (hq == 0) {
            s_off[pix][16] = ao1[0] + bo[16];
            s_off[pix][17] = ao1[1] + bo[17];
        }
    }
    __syncthreads();

    // ---------- phase B: coordinates + folded bilinear weights -> LDS ----------
    for (int it = t; it < 576; it += 256) {   // it = k*64 + pix
        int k = it >> 6;
        int p2 = it & 63;
        int wpp = w0 + p2;
        float dy = s_off[p2][2 * k];
        float dx = s_off[p2][2 * k + 1];
        float py = (float)(h + (k / 3) - 1) + dy;
        float px = (float)(wpp + (k % 3) - 1) + dx;
        float y0f = floorf(py), x0f = floorf(px);
        float fy = py - y0f, fx = px - x0f;
        float vy0 = (y0f >= 0.f  && y0f <= 127.f) ? 1.f : 0.f;
        float vy1 = (y0f >= -1.f && y0f <= 126.f) ? 1.f : 0.f;
        float vx0 = (x0f >= 0.f  && x0f <= 127.f) ? 1.f : 0.f;
        float vx1 = (x0f >= -1.f && x0f <= 126.f) ? 1.f : 0.f;
        float g0 = (1.f - fy) * (1.f - fx) * vy0 * vx0;
        float g1 = (1.f - fy) * fx         * vy0 * vx1;
        float g2 = fy * (1.f - fx)         * vy1 * vx0;
        float g3 = fy * fx                 * vy1 * vx1;
        int y0i = (int)fminf(fmaxf(y0f, 0.f), 127.f);
        int x0i = (int)fminf(fmaxf(x0f, 0.f), 127.f);
        int y1i = (int)fminf(fmaxf(y0f + 1.f, 0.f), 127.f);
        int x1i = (int)fminf(fmaxf(x0f + 1.f, 0.f), 127.f);
        unsigned a00 = (unsigned)(y0i * W + x0i);
        unsigned dxb = (unsigned)(x1i - x0i);
        unsigned dyb = (unsigned)(y1i - y0i);
        s_aw[it] = a00 | (dxb << 16) | (dyb << 17);
        _Float16 h0 = (_Float16)g0, h1 = (_Float16)g1, h2 = (_Float16)g2, h3 = (_Float16)g3;
        u32x4 wq;
        wq[0] = bcu((f16x2){h0, h0});
        wq[1] = bcu((f16x2){h1, h1});
        wq[2] = bcu((f16x2){h2, h2});
        wq[3] = bcu((f16x2){h3, h3});
        s_wgt[it] = wq;
    }
    __syncthreads();

    // ---------- phase C: deformable conv via MFMA ----------
    f32x4 acc[4] = {};
    #pragma unroll 2
    for (int kk = 0; kk < 18; ++kk) {
        int k = kk >> 1;
        unsigned aw = s_aw[(k << 6) | pix];
        u32x4 wq   = s_wgt[(k << 6) | pix];
        unsigned a00 = aw & 0xFFFFu;
        unsigned dxb = (aw >> 16) & 1u;
        unsigned a01 = a00 + dxb;
        unsigned a10 = a00 + (((aw >> 17) & 1u) << 7);
        unsigned a11 = a10 + dxb;
        int c0 = ((kk & 1) << 5) + (hq << 3);
        const _Float16* xc = xb + c0;
        u32x4 t00 = *(const u32x4*)(xc + (size_t)a00 * CIN);
        u32x4 t01 = *(const u32x4*)(xc + (size_t)a01 * CIN);
        u32x4 t10 = *(const u32x4*)(xc + (size_t)a10 * CIN);
        u32x4 t11 = *(const u32x4*)(xc + (size_t)a11 * CIN);
        f16x2 w00 = bch2(wq[0]), w01 = bch2(wq[1]), w10 = bch2(wq[2]), w11 = bch2(wq[3]);
        u32x4 fd;
        #pragma unroll
        for (int d = 0; d < 4; ++d) {
            f16x2 v = bch2(t00[d]) * w00 + bch2(t01[d]) * w01
                    + bch2(t10[d]) * w10 + bch2(t11[d]) * w11;
            fd[d] = bcu(v);
        }
        f16x8 bfrag = __builtin_bit_cast(f16x8, fd);
        const _Float16* arow = wac + pcol * 576 + (kk << 5) + (hq << 3);
        #pragma unroll
        for (int m = 0; m < 4; ++m) {
            f16x8 af = *(const f16x8*)(arow + m * 16 * 576);
            acc[m] = __builtin_amdgcn_mfma_f32_16x16x32_f16(af, bfrag, acc[m], 0, 0, 0);
        }
    }

    int ww = w0 + (wv << 4) + pcol;
    #pragma unroll
    for (int m = 0; m < 4; ++m) {
        #pragma unroll
        for (int r = 0; r < 4; ++r) {
            int co = (m << 4) + (hq << 2) + r;   // D: row=(lane>>4)*4+r, col=lane&15
            out[(((size_t)b * COUT + co) * H + h) * W + ww] = acc[m][r] + bconv[co];
        }
    }
}

extern "C" void kernel_launch(void* const* d_in, const int* in_sizes, int n_in,
                              void* d_out, int out_size, void* d_ws, size_t ws_size,
                              hipStream_t stream) {
    const float* x  = (const float*)d_in[0];
    const float* wo = (const float*)d_in[1];
    const float* bo = (const float*)d_in[2];
    const float* wc = (const float*)d_in[3];
    const float* bc = (const float*)d_in[4];
    float* out = (float*)d_out;

    _Float16* xt  = (_Float16*)d_ws;                              // 8*128*128*64 f16 = 16.78 MB
    _Float16* wao = (_Float16*)((char*)d_ws + (size_t)NB * H * W * CIN * 2);
    _Float16* wac = wao + 32 * 576;                               // +36.9 KB, +73.7 KB

    x_to_nhwc<<<NB * H, 256, 0, stream>>>(x, xt);
    prep_w<<<(96 * 576) / 256, 256, 0, stream>>>(wo, wc, wao, wac);
    deform_fused<<<NB * H * 2, 256, 0, stream>>>(xt, wao, wac, bo, bc, out);
}

// Round 3
// 187.540 us; speedup vs baseline: 1.8517x; 1.1097x over previous
//
#include <hip/hip_runtime.h>
#include <stdint.h>

#define H 128
#define W 128
#define CIN 64
#define COUT 64
#define NB 8

typedef __attribute__((ext_vector_type(4))) float f32x4;
typedef __attribute__((ext_vector_type(2))) _Float16 f16x2;
typedef __attribute__((ext_vector_type(8))) _Float16 f16x8;
typedef __attribute__((ext_vector_type(4))) unsigned int u32x4;

__device__ __forceinline__ f16x2 bch2(unsigned u) { return __builtin_bit_cast(f16x2, u); }
__device__ __forceinline__ unsigned bcu(f16x2 v) { return __builtin_bit_cast(unsigned, v); }

// ---- kernel 0: x NCHW f32 -> NHWC f16 (xt[b][h][w][c]) via LDS tile transpose
__global__ __launch_bounds__(256) void x_to_nhwc(const float* __restrict__ x,
                                                 _Float16* __restrict__ xt) {
    __shared__ _Float16 tile[W][68];
    int bh = blockIdx.x;
    int h = bh & (H - 1), b = bh >> 7;
    int t = threadIdx.x;
    #pragma unroll
    for (int i = 0; i < 8; ++i) {
        int idx = i * 256 + t;
        int c = idx >> 5;
        int w4 = (idx & 31) << 2;
        f32x4 v = *(const f32x4*)(x + (((size_t)(b * CIN + c) * H + h) * W + w4));
        #pragma unroll
        for (int j = 0; j < 4; ++j) tile[w4 + j][c] = (_Float16)v[j];
    }
    __syncthreads();
    _Float16* dst = xt + (size_t)bh * W * CIN;
    #pragma unroll
    for (int i = 0; i < 8; ++i) {
        int idx = i * 256 + t;
        int w = idx >> 4;
        int c4 = (idx & 15) << 2;
        *(uint2*)(dst + (size_t)w * CIN + c4) = *(const uint2*)&tile[w][c4];
    }
}

// ---- kernel 1: prepack weights to f16, k' = ktap*64 + c ordering
__global__ __launch_bounds__(256) void prep_w(const float* __restrict__ wo,
                                              const float* __restrict__ wc,
                                              _Float16* __restrict__ wao,
                                              _Float16* __restrict__ wac) {
    int t = blockIdx.x * 256 + threadIdx.x;
    if (t < 32 * 576) {
        int m = t / 576, r = t - m * 576, k = r >> 6, c = r & 63;
        wao[t] = (m < 18) ? (_Float16)wo[(m * 64 + c) * 9 + k] : (_Float16)0.f;
    } else if (t < 96 * 576) {
        int t2 = t - 32 * 576;
        int m = t2 / 576, r = t2 - m * 576, k = r >> 6, c = r & 63;
        wac[t2] = (_Float16)wc[(m * 64 + c) * 9 + k];
    }
}

// ---- kernel 2: fused offset-conv + coord setup + deformable conv, per-wave
// self-contained (16 pixels/wave), zero inter-wave deps, deep load pipelining.
__global__ __launch_bounds__(256, 3) void deform_fused(const _Float16* __restrict__ xt,
                                                       const _Float16* __restrict__ wao,
                                                       const _Float16* __restrict__ wac,
                                                       const float* __restrict__ bo,
                                                       const float* __restrict__ bconv,
                                                       float* __restrict__ out) {
    __shared__ unsigned s_aw[4][9][16];
    __shared__ u32x4   s_wq[4][9][16];

    int bid = blockIdx.x;
    int strip = ((bid & 7) << 8) | (bid >> 3);   // XCD swizzle: XCD k <- batch k
    int w0 = (strip & 1) << 6;
    int h  = (strip >> 1) & (H - 1);
    int b  = strip >> 8;

    int t = threadIdx.x;
    int lane = t & 63, wv = t >> 6;
    int pcol = lane & 15, hq = lane >> 4;
    int wp = w0 + (wv << 4) + pcol;

    const _Float16* xb = xt + (size_t)b * H * W * CIN;
    const _Float16* xh = xb + hq * 8;

    // ---------- phase A: offset conv via MFMA; all 18 x-loads issued upfront
    u32x4 xa[9][2];
    #pragma unroll
    for (int k = 0; k < 9; ++k) {
        int yy = h + k / 3 - 1;
        int xx = wp + k % 3 - 1;
        bool valid = ((unsigned)yy < (unsigned)H) && ((unsigned)xx < (unsigned)W);
        int yc = min(max(yy, 0), H - 1);
        int xc = min(max(xx, 0), W - 1);
        const _Float16* p = xh + (size_t)(yc * W + xc) * CIN;
        u32x4 v0 = *(const u32x4*)p;
        u32x4 v1 = *(const u32x4*)(p + 32);
        u32x4 z = {};
        xa[k][0] = valid ? v0 : z;
        xa[k][1] = valid ? v1 : z;
    }
    f32x4 ao0 = {}, ao1 = {};
    #pragma unroll
    for (int k = 0; k < 9; ++k) {
        const _Float16* arow = wao + pcol * 576 + k * 64 + hq * 8;
        f16x8 be = __builtin_bit_cast(f16x8, xa[k][0]);
        f16x8 bodd = __builtin_bit_cast(f16x8, xa[k][1]);
        ao0 = __builtin_amdgcn_mfma_f32_16x16x32_f16(*(const f16x8*)arow, be, ao0, 0, 0, 0);
        ao1 = __builtin_amdgcn_mfma_f32_16x16x32_f16(*(const f16x8*)(arow + 16 * 576), be, ao1, 0, 0, 0);
        ao0 = __builtin_amdgcn_mfma_f32_16x16x32_f16(*(const f16x8*)(arow + 32), bodd, ao0, 0, 0, 0);
        ao1 = __builtin_amdgcn_mfma_f32_16x16x32_f16(*(const f16x8*)(arow + 16 * 576 + 32), bodd, ao1, 0, 0, 0);
    }

    // ---------- per-lane coordinate setup for this lane's taps ----------
    auto setup = [&](int k, float dy, float dx) {
        float py = (float)(h + k / 3 - 1) + dy;
        float px = (float)(wp + k % 3 - 1) + dx;
        float y0f = floorf(py), x0f = floorf(px);
        float fy = py - y0f, fx = px - x0f;
        float vy0 = (y0f >= 0.f  && y0f <= 127.f) ? 1.f : 0.f;
        float vy1 = (y0f >= -1.f && y0f <= 126.f) ? 1.f : 0.f;
        float vx0 = (x0f >= 0.f  && x0f <= 127.f) ? 1.f : 0.f;
        float vx1 = (x0f >= -1.f && x0f <= 126.f) ? 1.f : 0.f;
        float g0 = (1.f - fy) * (1.f - fx) * vy0 * vx0;
        float g1 = (1.f - fy) * fx         * vy0 * vx1;
        float g2 = fy * (1.f - fx)         * vy1 * vx0;
        float g3 = fy * fx                 * vy1 * vx1;
        int y0i = (int)fminf(fmaxf(y0f, 0.f), 127.f);
        int x0i = (int)fminf(fmaxf(x0f, 0.f), 127.f);
        int y1i = (int)fminf(fmaxf(y0f + 1.f, 0.f), 127.f);
        int x1i = (int)fminf(fmaxf(x0f + 1.f, 0.f), 127.f);
        unsigned a00 = (unsigned)(y0i * W + x0i);
        unsigned dxb = (unsigned)(x1i - x0i);
        unsigned dyb = (unsigned)(y1i - y0i);
        _Float16 h0 = (_Float16)g0, h1 = (_Float16)g1, h2 = (_Float16)g2, h3 = (_Float16)g3;
        u32x4 wq;
        wq[0] = bcu((f16x2){h0, h0});
        wq[1] = bcu((f16x2){h1, h1});
        wq[2] = bcu((f16x2){h2, h2});
        wq[3] = bcu((f16x2){h3, h3});
        s_aw[wv][k][pcol] = a00 | (dxb << 16) | (dyb << 17);
        s_wq[wv][k][pcol] = wq;
    };
    f32x4 bo4 = *(const f32x4*)(bo + 4 * hq);
    setup(2 * hq,     ao0[0] + bo4[0], ao0[1] + bo4[1]);
    setup(2 * hq + 1, ao0[2] + bo4[2], ao0[3] + bo4[3]);
    if (hq == 0) setup(8, ao1[0] + bo[16], ao1[1] + bo[17]);
    __syncthreads();

    // ---------- phase C: deformable conv; 16 independent loads per tap, full unroll
    f32x4 acc[4] = {};
    #pragma unroll
    for (int k = 0; k < 9; ++k) {
        unsigned aw = s_aw[wv][k][pcol];
        u32x4 wq = s_wq[wv][k][pcol];
        unsigned a00 = aw & 0xFFFFu;
        unsigned dxb = (aw >> 16) & 1u;
        unsigned a01 = a00 + dxb;
        unsigned a10 = a00 + (((aw >> 17) & 1u) << 7);
        unsigned a11 = a10 + dxb;
        const _Float16* p00 = xh + (size_t)a00 * CIN;
        const _Float16* p01 = xh + (size_t)a01 * CIN;
        const _Float16* p10 = xh + (size_t)a10 * CIN;
        const _Float16* p11 = xh + (size_t)a11 * CIN;
        u32x4 g00 = *(const u32x4*)p00,        g01 = *(const u32x4*)p01;
        u32x4 g10 = *(const u32x4*)p10,        g11 = *(const u32x4*)p11;
        u32x4 h00 = *(const u32x4*)(p00 + 32), h01 = *(const u32x4*)(p01 + 32);
        u32x4 h10 = *(const u32x4*)(p10 + 32), h11 = *(const u32x4*)(p11 + 32);
        f16x2 w00 = bch2(wq[0]), w01 = bch2(wq[1]), w10 = bch2(wq[2]), w11 = bch2(wq[3]);
        u32x4 fe, fo;
        #pragma unroll
        for (int d = 0; d < 4; ++d) {
            f16x2 ve = bch2(g00[d]) * w00 + bch2(g01[d]) * w01
                     + bch2(g10[d]) * w10 + bch2(g11[d]) * w11;
            f16x2 vo = bch2(h00[d]) * w00 + bch2(h01[d]) * w01
                     + bch2(h10[d]) * w10 + bch2(h11[d]) * w11;
            fe[d] = bcu(ve);
            fo[d] = bcu(vo);
        }
        f16x8 bfe = __builtin_bit_cast(f16x8, fe);
        f16x8 bfo = __builtin_bit_cast(f16x8, fo);
        const _Float16* arow = wac + pcol * 576 + k * 64 + hq * 8;
        #pragma unroll
        for (int m = 0; m < 4; ++m) {
            f16x8 ae = *(const f16x8*)(arow + m * 16 * 576);
            acc[m] = __builtin_amdgcn_mfma_f32_16x16x32_f16(ae, bfe, acc[m], 0, 0, 0);
        }
        #pragma unroll
        for (int m = 0; m < 4; ++m) {
            f16x8 aodd = *(const f16x8*)(arow + m * 16 * 576 + 32);
            acc[m] = __builtin_amdgcn_mfma_f32_16x16x32_f16(aodd, bfo, acc[m], 0, 0, 0);
        }
    }

    #pragma unroll
    for (int m = 0; m < 4; ++m) {
        f32x4 bc4 = *(const f32x4*)(bconv + m * 16 + hq * 4);
        #pragma unroll
        for (int r = 0; r < 4; ++r) {
            int co = (m << 4) + (hq << 2) + r;
            out[(((size_t)b * COUT + co) * H + h) * W + wp] = acc[m][r] + bc4[r];
        }
    }
}

extern "C" void kernel_launch(void* const* d_in, const int* in_sizes, int n_in,
                              void* d_out, int out_size, void* d_ws, size_t ws_size,
                              hipStream_t stream) {
    const float* x  = (const float*)d_in[0];
    const float* wo = (const float*)d_in[1];
    const float* bo = (const float*)d_in[2];
    const float* wc = (const float*)d_in[3];
    const float* bc = (const float*)d_in[4];
    float* out = (float*)d_out;

    _Float16* xt  = (_Float16*)d_ws;
    _Float16* wao = (_Float16*)((char*)d_ws + (size_t)NB * H * W * CIN * 2);
    _Float16* wac = wao + 32 * 576;

    x_to_nhwc<<<NB * H, 256, 0, stream>>>(x, xt);
    prep_w<<<(96 * 576) / 256, 256, 0, stream>>>(wo, wc, wao, wac);
    deform_fused<<<NB * H * 2, 256, 0, stream>>>(xt, wao, wac, bo, bc, out);
}

// Round 4
// 70.914 us; speedup vs baseline: 4.8970x; 2.6446x over previous
//
#include <hip/hip_runtime.h>
#include <stdint.h>

#define H 128
#define W 128
#define CIN 64
#define COUT 64
#define NB 8
#define CW 68       // staged cols per row
#define PLANE 340   // 5*68 slots per chunk-plane

typedef __attribute__((ext_vector_type(4))) float f32x4;
typedef __attribute__((ext_vector_type(2))) _Float16 f16x2;
typedef __attribute__((ext_vector_type(8))) _Float16 f16x8;
typedef __attribute__((ext_vector_type(4))) unsigned int u32x4;
typedef __attribute__((ext_vector_type(2))) unsigned int u32x2;

__device__ __forceinline__ f16x2 bch2(unsigned u) { return __builtin_bit_cast(f16x2, u); }
__device__ __forceinline__ unsigned bcu(f16x2 v) { return __builtin_bit_cast(unsigned, v); }

// ---- kernel 0: x NCHW f32 -> NHWC f16 (xt[b][h][w][c]) via LDS tile transpose
__global__ __launch_bounds__(256) void x_to_nhwc(const float* __restrict__ x,
                                                 _Float16* __restrict__ xt) {
    __shared__ _Float16 tile[W][68];
    int bh = blockIdx.x;
    int h = bh & (H - 1), b = bh >> 7;
    int t = threadIdx.x;
    #pragma unroll
    for (int i = 0; i < 8; ++i) {
        int idx = i * 256 + t;
        int c = idx >> 5;
        int w4 = (idx & 31) << 2;
        f32x4 v = *(const f32x4*)(x + (((size_t)(b * CIN + c) * H + h) * W + w4));
        #pragma unroll
        for (int j = 0; j < 4; ++j) tile[w4 + j][c] = (_Float16)v[j];
    }
    __syncthreads();
    _Float16* dst = xt + (size_t)bh * W * CIN;
    #pragma unroll
    for (int i = 0; i < 8; ++i) {
        int idx = i * 256 + t;
        int w = idx >> 4;
        int c4 = (idx & 15) << 2;
        *(uint2*)(dst + (size_t)w * CIN + c4) = *(const uint2*)&tile[w][c4];
    }
}

// ---- kernel 1: prepack weights, MFMA-lane-coalesced layout
//  wao2[((kk*2+m)*64 + l)*8 + j] ; wac2[((kk*4+m)*64 + l)*8 + j]
//  element = w[cout = m*16+(l&15)][cin = (kk&1)*32 + (l>>4)*8 + j][tap = kk>>1]
__global__ __launch_bounds__(256) void prep_w(const float* __restrict__ wo,
                                              const float* __restrict__ wc,
                                              _Float16* __restrict__ wao2,
                                              _Float16* __restrict__ wac2) {
    int t = blockIdx.x * 256 + threadIdx.x;
    if (t < 18432) {
        int j = t & 7, l = (t >> 3) & 63, m = (t >> 9) & 1, kk = t >> 10;
        int cout = m * 16 + (l & 15);
        int cin = (kk & 1) * 32 + ((l >> 4) << 3) + j;
        wao2[t] = (cout < 18) ? (_Float16)wo[(cout * 64 + cin) * 9 + (kk >> 1)]
                              : (_Float16)0.f;
    } else if (t < 18432 + 36864) {
        int u = t - 18432;
        int j = u & 7, l = (u >> 3) & 63, m = (u >> 9) & 3, kk = u >> 11;
        int cout = m * 16 + (l & 15);
        int cin = (kk & 1) * 32 + ((l >> 4) << 3) + j;
        wac2[u] = (_Float16)wc[(cout * 64 + cin) * 9 + (kk >> 1)];
    }
}

// ---- kernel 2: fused offset-conv + coord setup + deformable conv.
// x window (5 rows x 68 cols) staged in LDS chunk-planes; bilinear corners read
// via ds_read_b128; rare far-offset lanes fall back to global gathers.
__global__ __launch_bounds__(256, 3) void deform_fused(const _Float16* __restrict__ xt,
                                                       const _Float16* __restrict__ wao2,
                                                       const _Float16* __restrict__ wac2,
                                                       const float* __restrict__ bo,
                                                       const float* __restrict__ bconv,
                                                       float* __restrict__ out) {
    __shared__ u32x4   s_x[8 * PLANE];   // [chunk c/8][row*CW+col] 16B each = 43.5 KB
    __shared__ unsigned s_aw[4][9][16];  // s00 | dxb<<9 | dyb<<10 | oow<<11 | a00<<12
    __shared__ u32x2   s_wq[4][9][16];   // {g0,g1},{g2,g3} packed f16

    int bid = blockIdx.x;
    int strip = ((bid & 7) << 8) | (bid >> 3);   // XCD swizzle: XCD k <- batch k
    int w0 = (strip & 1) << 6;
    int h  = (strip >> 1) & (H - 1);
    int b  = strip >> 8;

    int r_lo = max(0, h - 2),  r_hi = min(H - 1, h + 2);
    int c_lo = max(0, w0 - 2), c_hi = min(W - 1, w0 + 65);
    int nr = r_hi - r_lo + 1,  nc = c_hi - c_lo + 1;

    int t = threadIdx.x;
    int lane = t & 63, wv = t >> 6;
    int pcol = lane & 15, hq = lane >> 4;
    int wp = w0 + (wv << 4) + pcol;

    const _Float16* xb = xt + (size_t)b * H * W * CIN;

    // ---------- stage x window into LDS chunk-planes (coalesced) ----------
    for (int rr = 0; rr < nr; ++rr) {
        const _Float16* xrow = xb + (size_t)((r_lo + rr) * W + c_lo) * CIN;
        for (int i = t; i < nc * 8; i += 256) {
            int cs = i >> 3, ch = i & 7;
            u32x4 v = *(const u32x4*)(xrow + (size_t)cs * CIN + (ch << 3));
            s_x[ch * PLANE + rr * CW + cs] = v;
        }
    }
    __syncthreads();

    // ---------- phase A: offset conv via MFMA, x from LDS ----------
    f32x4 ao0 = {}, ao1 = {};
    #pragma unroll
    for (int k = 0; k < 9; ++k) {
        int yy = h + k / 3 - 1;
        int xx = wp + k % 3 - 1;
        bool valid = ((unsigned)yy < (unsigned)H) && ((unsigned)xx < (unsigned)W);
        int yc = min(max(yy, 0), H - 1);
        int xc = min(max(xx, 0), W - 1);
        int s = (yc - r_lo) * CW + (xc - c_lo);
        u32x4 ve = s_x[hq * PLANE + s];
        u32x4 vo = s_x[(4 + hq) * PLANE + s];
        u32x4 z = {};
        if (!valid) { ve = z; vo = z; }
        f16x8 be = __builtin_bit_cast(f16x8, ve);
        f16x8 bod = __builtin_bit_cast(f16x8, vo);
        const _Float16* wb = wao2 + (size_t)(4 * k) * 512 + lane * 8;
        ao0 = __builtin_amdgcn_mfma_f32_16x16x32_f16(*(const f16x8*)(wb), be, ao0, 0, 0, 0);
        ao1 = __builtin_amdgcn_mfma_f32_16x16x32_f16(*(const f16x8*)(wb + 512), be, ao1, 0, 0, 0);
        ao0 = __builtin_amdgcn_mfma_f32_16x16x32_f16(*(const f16x8*)(wb + 1024), bod, ao0, 0, 0, 0);
        ao1 = __builtin_amdgcn_mfma_f32_16x16x32_f16(*(const f16x8*)(wb + 1536), bod, ao1, 0, 0, 0);
    }

    // ---------- per-lane coordinate setup ----------
    auto setup = [&](int k, float dy, float dx) {
        float py = (float)(h + k / 3 - 1) + dy;
        float px = (float)(wp + k % 3 - 1) + dx;
        float y0f = floorf(py), x0f = floorf(px);
        float fy = py - y0f, fx = px - x0f;
        float vy0 = (y0f >= 0.f  && y0f <= 127.f) ? 1.f : 0.f;
        float vy1 = (y0f >= -1.f && y0f <= 126.f) ? 1.f : 0.f;
        float vx0 = (x0f >= 0.f  && x0f <= 127.f) ? 1.f : 0.f;
        float vx1 = (x0f >= -1.f && x0f <= 126.f) ? 1.f : 0.f;
        float g0 = (1.f - fy) * (1.f - fx) * vy0 * vx0;
        float g1 = (1.f - fy) * fx         * vy0 * vx1;
        float g2 = fy * (1.f - fx)         * vy1 * vx0;
        float g3 = fy * fx                 * vy1 * vx1;
        int y0i = (int)fminf(fmaxf(y0f, 0.f), 127.f);
        int x0i = (int)fminf(fmaxf(x0f, 0.f), 127.f);
        int y1i = (int)fminf(fmaxf(y0f + 1.f, 0.f), 127.f);
        int x1i = (int)fminf(fmaxf(x0f + 1.f, 0.f), 127.f);
        unsigned dxb = (unsigned)(x1i - x0i);
        unsigned dyb = (unsigned)(y1i - y0i);
        bool inw = (y0i >= r_lo) && (y1i <= r_hi) && (x0i >= c_lo) && (x1i <= c_hi);
        unsigned s00 = inw ? (unsigned)((y0i - r_lo) * CW + (x0i - c_lo)) : 0u;
        unsigned a00 = (unsigned)(y0i * W + x0i);
        s_aw[wv][k][pcol] = s00 | (dxb << 9) | (dyb << 10) | (inw ? 0u : (1u << 11)) | (a00 << 12);
        _Float16 h0 = (_Float16)g0, h1 = (_Float16)g1, h2 = (_Float16)g2, h3 = (_Float16)g3;
        u32x2 wq;
        wq[0] = bcu((f16x2){h0, h1});
        wq[1] = bcu((f16x2){h2, h3});
        s_wq[wv][k][pcol] = wq;
    };
    f32x4 bo4 = *(const f32x4*)(bo + 4 * hq);
    setup(2 * hq,     ao0[0] + bo4[0], ao0[1] + bo4[1]);
    setup(2 * hq + 1, ao0[2] + bo4[2], ao0[3] + bo4[3]);
    if (hq == 0) setup(8, ao1[0] + bo[16], ao1[1] + bo[17]);
    __syncthreads();

    // ---------- phase C: deformable conv; corners from LDS ----------
    const _Float16* xh = xb + (hq << 3);
    f32x4 acc[4] = {};
    #pragma unroll
    for (int k = 0; k < 9; ++k) {
        unsigned aw = s_aw[wv][k][pcol];
        u32x2 wq = s_wq[wv][k][pcol];
        unsigned s00 = aw & 511u;
        unsigned dxb = (aw >> 9) & 1u;
        unsigned dyb = (aw >> 10) & 1u;
        unsigned s01 = s00 + dxb;
        unsigned s10 = s00 + dyb * CW;
        unsigned s11 = s10 + dxb;
        u32x4 e00 = s_x[hq * PLANE + s00], e01 = s_x[hq * PLANE + s01];
        u32x4 e10 = s_x[hq * PLANE + s10], e11 = s_x[hq * PLANE + s11];
        u32x4 o00 = s_x[(4 + hq) * PLANE + s00], o01 = s_x[(4 + hq) * PLANE + s01];
        u32x4 o10 = s_x[(4 + hq) * PLANE + s10], o11 = s_x[(4 + hq) * PLANE + s11];
        if (__builtin_expect((aw & (1u << 11)) != 0u, 0)) {   // rare far-offset fallback
            unsigned a00 = aw >> 12;
            unsigned a01 = a00 + dxb;
            unsigned a10 = a00 + (dyb << 7);
            unsigned a11 = a10 + dxb;
            const _Float16* p00 = xh + (size_t)a00 * CIN;
            const _Float16* p01 = xh + (size_t)a01 * CIN;
            const _Float16* p10 = xh + (size_t)a10 * CIN;
            const _Float16* p11 = xh + (size_t)a11 * CIN;
            e00 = *(const u32x4*)p00; o00 = *(const u32x4*)(p00 + 32);
            e01 = *(const u32x4*)p01; o01 = *(const u32x4*)(p01 + 32);
            e10 = *(const u32x4*)p10; o10 = *(const u32x4*)(p10 + 32);
            e11 = *(const u32x4*)p11; o11 = *(const u32x4*)(p11 + 32);
        }
        f16x2 w01p = bch2(wq[0]);
        f16x2 w23p = bch2(wq[1]);
        f16x2 w00d = (f16x2){w01p[0], w01p[0]};
        f16x2 w01d = (f16x2){w01p[1], w01p[1]};
        f16x2 w10d = (f16x2){w23p[0], w23p[0]};
        f16x2 w11d = (f16x2){w23p[1], w23p[1]};
        u32x4 fe, fo;
        #pragma unroll
        for (int d = 0; d < 4; ++d) {
            f16x2 ve = bch2(e00[d]) * w00d + bch2(e01[d]) * w01d
                     + bch2(e10[d]) * w10d + bch2(e11[d]) * w11d;
            f16x2 vo = bch2(o00[d]) * w00d + bch2(o01[d]) * w01d
                     + bch2(o10[d]) * w10d + bch2(o11[d]) * w11d;
            fe[d] = bcu(ve);
            fo[d] = bcu(vo);
        }
        f16x8 bfe = __builtin_bit_cast(f16x8, fe);
        f16x8 bfo = __builtin_bit_cast(f16x8, fo);
        const _Float16* ab = wac2 + (size_t)(8 * k) * 512 + lane * 8;
        #pragma unroll
        for (int m = 0; m < 4; ++m)
            acc[m] = __builtin_amdgcn_mfma_f32_16x16x32_f16(*(const f16x8*)(ab + m * 512), bfe, acc[m], 0, 0, 0);
        #pragma unroll
        for (int m = 0; m < 4; ++m)
            acc[m] = __builtin_amdgcn_mfma_f32_16x16x32_f16(*(const f16x8*)(ab + (4 + m) * 512), bfo, acc[m], 0, 0, 0);
    }

    #pragma unroll
    for (int m = 0; m < 4; ++m) {
        f32x4 bc4 = *(const f32x4*)(bconv + m * 16 + (hq << 2));
        #pragma unroll
        for (int r = 0; r < 4; ++r) {
            int co = (m << 4) + (hq << 2) + r;
            out[(((size_t)b * COUT + co) * H + h) * W + wp] = acc[m][r] + bc4[r];
        }
    }
}

extern "C" void kernel_launch(void* const* d_in, const int* in_sizes, int n_in,
                              void* d_out, int out_size, void* d_ws, size_t ws_size,
                              hipStream_t stream) {
    const float* x  = (const float*)d_in[0];
    const float* wo = (const float*)d_in[1];
    const float* bo = (const float*)d_in[2];
    const float* wc = (const float*)d_in[3];
    const float* bc = (const float*)d_in[4];
    float* out = (float*)d_out;

    _Float16* xt   = (_Float16*)d_ws;                                   // 16.78 MB
    _Float16* wao2 = (_Float16*)((char*)d_ws + (size_t)NB * H * W * CIN * 2);
    _Float16* wac2 = wao2 + 18432;                                      // +36.9 KB, +73.7 KB

    x_to_nhwc<<<NB * H, 256, 0, stream>>>(x, xt);
    prep_w<<<(18432 + 36864 + 255) / 256, 256, 0, stream>>>(wo, wc, wao2, wac2);
    deform_fused<<<NB * H * 2, 256, 0, stream>>>(xt, wao2, wac2, bo, bc, out);
}

// Round 5
// 64.749 us; speedup vs baseline: 5.3632x; 1.0952x over previous
//
#include <hip/hip_runtime.h>
#include <stdint.h>

#define H 128
#define W 128
#define CIN 64
#define COUT 64
#define NB 8
#define WR 4        // pixel rows per block
#define WC 16       // pixel cols per block
#define CW 20       // staged cols per window row (WC+4)
#define NROW 8      // staged rows (WR+4)
#define PLANE 162   // slots per chunk-plane; 162 % 8 == 2 -> quarter decorrelation

typedef __attribute__((ext_vector_type(4))) float f32x4;
typedef __attribute__((ext_vector_type(2))) _Float16 f16x2;
typedef __attribute__((ext_vector_type(8))) _Float16 f16x8;
typedef __attribute__((ext_vector_type(4))) unsigned int u32x4;

__device__ __forceinline__ f16x2 bch2(unsigned u) { return __builtin_bit_cast(f16x2, u); }
__device__ __forceinline__ unsigned bcu(f16x2 v) { return __builtin_bit_cast(unsigned, v); }

// ---- kernel 0: x NCHW f32 -> NHWC f16 (xt[b][h][w][c]) via LDS tile transpose
__global__ __launch_bounds__(256) void x_to_nhwc(const float* __restrict__ x,
                                                 _Float16* __restrict__ xt) {
    __shared__ _Float16 tile[W][68];
    int bh = blockIdx.x;
    int h = bh & (H - 1), b = bh >> 7;
    int t = threadIdx.x;
    #pragma unroll
    for (int i = 0; i < 8; ++i) {
        int idx = i * 256 + t;
        int c = idx >> 5;
        int w4 = (idx & 31) << 2;
        f32x4 v = *(const f32x4*)(x + (((size_t)(b * CIN + c) * H + h) * W + w4));
        #pragma unroll
        for (int j = 0; j < 4; ++j) tile[w4 + j][c] = (_Float16)v[j];
    }
    __syncthreads();
    _Float16* dst = xt + (size_t)bh * W * CIN;
    #pragma unroll
    for (int i = 0; i < 8; ++i) {
        int idx = i * 256 + t;
        int w = idx >> 4;
        int c4 = (idx & 15) << 2;
        *(uint2*)(dst + (size_t)w * CIN + c4) = *(const uint2*)&tile[w][c4];
    }
}

// ---- kernel 1: prepack weights, MFMA-lane-coalesced layout
//  wao2[((kk*2+m)*64 + l)*8 + j] ; wac2[((kk*4+m)*64 + l)*8 + j]
//  element = w[cout = m*16+(l&15)][cin = (kk&1)*32 + (l>>4)*8 + j][tap = kk>>1]
__global__ __launch_bounds__(256) void prep_w(const float* __restrict__ wo,
                                              const float* __restrict__ wc,
                                              _Float16* __restrict__ wao2,
                                              _Float16* __restrict__ wac2) {
    int t = blockIdx.x * 256 + threadIdx.x;
    if (t < 18432) {
        int j = t & 7, l = (t >> 3) & 63, m = (t >> 9) & 1, kk = t >> 10;
        int cout = m * 16 + (l & 15);
        int cin = (kk & 1) * 32 + ((l >> 4) << 3) + j;
        wao2[t] = (cout < 18) ? (_Float16)wo[(cout * 64 + cin) * 9 + (kk >> 1)]
                              : (_Float16)0.f;
    } else if (t < 18432 + 36864) {
        int u = t - 18432;
        int j = u & 7, l = (u >> 3) & 63, m = (u >> 9) & 3, kk = u >> 11;
        int cout = m * 16 + (l & 15);
        int cin = (kk & 1) * 32 + ((l >> 4) << 3) + j;
        wac2[u] = (_Float16)wc[(cout * 64 + cin) * 9 + (kk >> 1)];
    }
}

// ---- kernel 2: fused offset-conv + coord setup + deformable conv.
// Block = 4 waves, each wave owns one pixel row of 16 (4x16 tile). x window
// (<=8 rows x 20 cols) staged in LDS chunk-planes, stride 162 (bank-decorrelated).
__global__ __launch_bounds__(256, 4) void deform_fused(const _Float16* __restrict__ xt,
                                                       const _Float16* __restrict__ wao2,
                                                       const _Float16* __restrict__ wac2,
                                                       const float* __restrict__ bo,
                                                       const float* __restrict__ bconv,
                                                       float* __restrict__ out) {
    __shared__ u32x4   s_x[8 * PLANE];   // [chunk c/8][row*CW+col], 16B slots = 20.7 KB
    __shared__ unsigned s_aw[4][9][16];  // s00 | dxb<<9 | dyb<<10 | oow<<11 | a00<<12
    __shared__ u32x4   s_wq[4][9][16];   // dup-packed f16 bilinear weights

    int bid = blockIdx.x;
    int b = bid & 7;                      // XCD swizzle: XCD k <- batch k
    int r = bid >> 3;                     // 0..255 within batch
    int h0 = ((r >> 3) & 31) << 2;
    int w0 = (r & 7) << 4;

    int r_lo = max(0, h0 - 2), r_hi = min(H - 1, h0 + 5);
    int c_lo = max(0, w0 - 2), c_hi = min(W - 1, w0 + WC + 1);
    int nr = r_hi - r_lo + 1, nc = c_hi - c_lo + 1;

    int t = threadIdx.x;
    int lane = t & 63, wv = t >> 6;
    int pcol = lane & 15, hq = lane >> 4;
    int h = h0 + wv;
    int wp = w0 + pcol;

    const _Float16* xb = xt + (size_t)b * H * W * CIN;

    // ---------- stage x window into LDS chunk-planes ----------
    {
        int cs = t >> 3, ch = t & 7;
        bool act = t < nc * 8;
        for (int rr = 0; rr < nr; ++rr) {
            if (act) {
                u32x4 v = *(const u32x4*)(xb + (size_t)((r_lo + rr) * W + c_lo + cs) * CIN + (ch << 3));
                s_x[ch * PLANE + rr * CW + cs] = v;
            }
        }
    }
    __syncthreads();

    // ---------- phase A: offset conv via MFMA, x from LDS ----------
    f32x4 ao0 = {}, ao1 = {};
    #pragma unroll
    for (int k = 0; k < 9; ++k) {
        int yy = h + k / 3 - 1;
        int xx = wp + k % 3 - 1;
        bool valid = ((unsigned)yy < (unsigned)H) && ((unsigned)xx < (unsigned)W);
        int yc = min(max(yy, 0), H - 1);
        int xc = min(max(xx, 0), W - 1);
        int s = (yc - r_lo) * CW + (xc - c_lo);
        u32x4 ve = s_x[hq * PLANE + s];
        u32x4 vo = s_x[(4 + hq) * PLANE + s];
        u32x4 z = {};
        if (!valid) { ve = z; vo = z; }
        f16x8 be = __builtin_bit_cast(f16x8, ve);
        f16x8 bod = __builtin_bit_cast(f16x8, vo);
        const _Float16* wb = wao2 + (size_t)(4 * k) * 512 + lane * 8;
        ao0 = __builtin_amdgcn_mfma_f32_16x16x32_f16(*(const f16x8*)(wb), be, ao0, 0, 0, 0);
        ao1 = __builtin_amdgcn_mfma_f32_16x16x32_f16(*(const f16x8*)(wb + 512), be, ao1, 0, 0, 0);
        ao0 = __builtin_amdgcn_mfma_f32_16x16x32_f16(*(const f16x8*)(wb + 1024), bod, ao0, 0, 0, 0);
        ao1 = __builtin_amdgcn_mfma_f32_16x16x32_f16(*(const f16x8*)(wb + 1536), bod, ao1, 0, 0, 0);
    }

    // ---------- per-lane coordinate setup ----------
    auto setup = [&](int k, float dy, float dx) {
        float py = (float)(h + k / 3 - 1) + dy;
        float px = (float)(wp + k % 3 - 1) + dx;
        float y0f = floorf(py), x0f = floorf(px);
        float fy = py - y0f, fx = px - x0f;
        float vy0 = (y0f >= 0.f  && y0f <= 127.f) ? 1.f : 0.f;
        float vy1 = (y0f >= -1.f && y0f <= 126.f) ? 1.f : 0.f;
        float vx0 = (x0f >= 0.f  && x0f <= 127.f) ? 1.f : 0.f;
        float vx1 = (x0f >= -1.f && x0f <= 126.f) ? 1.f : 0.f;
        float g0 = (1.f - fy) * (1.f - fx) * vy0 * vx0;
        float g1 = (1.f - fy) * fx         * vy0 * vx1;
        float g2 = fy * (1.f - fx)         * vy1 * vx0;
        float g3 = fy * fx                 * vy1 * vx1;
        int y0i = (int)fminf(fmaxf(y0f, 0.f), 127.f);
        int x0i = (int)fminf(fmaxf(x0f, 0.f), 127.f);
        int y1i = (int)fminf(fmaxf(y0f + 1.f, 0.f), 127.f);
        int x1i = (int)fminf(fmaxf(x0f + 1.f, 0.f), 127.f);
        unsigned dxb = (unsigned)(x1i - x0i);
        unsigned dyb = (unsigned)(y1i - y0i);
        bool inw = (y0i >= r_lo) && (y1i <= r_hi) && (x0i >= c_lo) && (x1i <= c_hi);
        unsigned s00 = inw ? (unsigned)((y0i - r_lo) * CW + (x0i - c_lo)) : 0u;
        unsigned a00 = (unsigned)(y0i * W + x0i);
        s_aw[wv][k][pcol] = s00 | (dxb << 9) | (dyb << 10) | (inw ? 0u : (1u << 11)) | (a00 << 12);
        _Float16 h0h = (_Float16)g0, h1h = (_Float16)g1, h2h = (_Float16)g2, h3h = (_Float16)g3;
        u32x4 wq;
        wq[0] = bcu((f16x2){h0h, h0h});
        wq[1] = bcu((f16x2){h1h, h1h});
        wq[2] = bcu((f16x2){h2h, h2h});
        wq[3] = bcu((f16x2){h3h, h3h});
        s_wq[wv][k][pcol] = wq;
    };
    f32x4 bo4 = *(const f32x4*)(bo + 4 * hq);
    setup(2 * hq,     ao0[0] + bo4[0], ao0[1] + bo4[1]);
    setup(2 * hq + 1, ao0[2] + bo4[2], ao0[3] + bo4[3]);
    if (hq == 0) setup(8, ao1[0] + bo[16], ao1[1] + bo[17]);
    __syncthreads();

    // ---------- phase C: deformable conv; corners from LDS ----------
    const _Float16* xh = xb + (hq << 3);
    f32x4 acc[4] = {};
    #pragma unroll
    for (int k = 0; k < 9; ++k) {
        unsigned aw = s_aw[wv][k][pcol];
        u32x4 wq = s_wq[wv][k][pcol];
        unsigned s00 = aw & 511u;
        unsigned dxb = (aw >> 9) & 1u;
        unsigned dyb = (aw >> 10) & 1u;
        unsigned s01 = s00 + dxb;
        unsigned s10 = s00 + dyb * CW;
        unsigned s11 = s10 + dxb;
        u32x4 e00 = s_x[hq * PLANE + s00], e01 = s_x[hq * PLANE + s01];
        u32x4 e10 = s_x[hq * PLANE + s10], e11 = s_x[hq * PLANE + s11];
        u32x4 o00 = s_x[(4 + hq) * PLANE + s00], o01 = s_x[(4 + hq) * PLANE + s01];
        u32x4 o10 = s_x[(4 + hq) * PLANE + s10], o11 = s_x[(4 + hq) * PLANE + s11];
        if (__builtin_expect((aw & (1u << 11)) != 0u, 0)) {   // rare far-offset fallback
            unsigned a00 = aw >> 12;
            unsigned a01 = a00 + dxb;
            unsigned a10 = a00 + (dyb << 7);
            unsigned a11 = a10 + dxb;
            const _Float16* p00 = xh + (size_t)a00 * CIN;
            const _Float16* p01 = xh + (size_t)a01 * CIN;
            const _Float16* p10 = xh + (size_t)a10 * CIN;
            const _Float16* p11 = xh + (size_t)a11 * CIN;
            e00 = *(const u32x4*)p00; o00 = *(const u32x4*)(p00 + 32);
            e01 = *(const u32x4*)p01; o01 = *(const u32x4*)(p01 + 32);
            e10 = *(const u32x4*)p10; o10 = *(const u32x4*)(p10 + 32);
            e11 = *(const u32x4*)p11; o11 = *(const u32x4*)(p11 + 32);
        }
        f16x2 w00d = bch2(wq[0]), w01d = bch2(wq[1]), w10d = bch2(wq[2]), w11d = bch2(wq[3]);
        u32x4 fe, fo;
        #pragma unroll
        for (int d = 0; d < 4; ++d) {
            f16x2 ve = bch2(e00[d]) * w00d + bch2(e01[d]) * w01d
                     + bch2(e10[d]) * w10d + bch2(e11[d]) * w11d;
            f16x2 vo = bch2(o00[d]) * w00d + bch2(o01[d]) * w01d
                     + bch2(o10[d]) * w10d + bch2(o11[d]) * w11d;
            fe[d] = bcu(ve);
            fo[d] = bcu(vo);
        }
        f16x8 bfe = __builtin_bit_cast(f16x8, fe);
        f16x8 bfo = __builtin_bit_cast(f16x8, fo);
        const _Float16* ab = wac2 + (size_t)(8 * k) * 512 + lane * 8;
        #pragma unroll
        for (int m = 0; m < 4; ++m)
            acc[m] = __builtin_amdgcn_mfma_f32_16x16x32_f16(*(const f16x8*)(ab + m * 512), bfe, acc[m], 0, 0, 0);
        #pragma unroll
        for (int m = 0; m < 4; ++m)
            acc[m] = __builtin_amdgcn_mfma_f32_16x16x32_f16(*(const f16x8*)(ab + (4 + m) * 512), bfo, acc[m], 0, 0, 0);
    }

    #pragma unroll
    for (int m = 0; m < 4; ++m) {
        f32x4 bc4 = *(const f32x4*)(bconv + m * 16 + (hq << 2));
        #pragma unroll
        for (int r2 = 0; r2 < 4; ++r2) {
            int co = (m << 4) + (hq << 2) + r2;
            out[(((size_t)b * COUT + co) * H + h) * W + wp] = acc[m][r2] + bc4[r2];
        }
    }
}

extern "C" void kernel_launch(void* const* d_in, const int* in_sizes, int n_in,
                              void* d_out, int out_size, void* d_ws, size_t ws_size,
                              hipStream_t stream) {
    const float* x  = (const float*)d_in[0];
    const float* wo = (const float*)d_in[1];
    const float* bo = (const float*)d_in[2];
    const float* wc = (const float*)d_in[3];
    const float* bc = (const float*)d_in[4];
    float* out = (float*)d_out;

    _Float16* xt   = (_Float16*)d_ws;                                   // 16.78 MB
    _Float16* wao2 = (_Float16*)((char*)d_ws + (size_t)NB * H * W * CIN * 2);
    _Float16* wac2 = wao2 + 18432;

    x_to_nhwc<<<NB * H, 256, 0, stream>>>(x, xt);
    prep_w<<<(18432 + 36864 + 255) / 256, 256, 0, stream>>>(wo, wc, wao2, wac2);
    deform_fused<<<NB * H * W / (WR * WC), 256, 0, stream>>>(xt, wao2, wac2, bo, bc, out);
}

// Round 6
// 54.987 us; speedup vs baseline: 6.3153x; 1.1775x over previous
//
#include <hip/hip_runtime.h>
#include <stdint.h>

#define H 128
#define W 128
#define CIN 64
#define COUT 64
#define NB 8
#define WR 4        // pixel rows per block
#define WC 16       // pixel cols per block
#define CW 20       // staged cols per window row (WC+4)
#define PLANE 162   // slots per chunk-plane; 162 % 8 == 2 -> quarter decorrelation

typedef __attribute__((ext_vector_type(4))) float f32x4;
typedef __attribute__((ext_vector_type(2))) _Float16 f16x2;
typedef __attribute__((ext_vector_type(8))) _Float16 f16x8;
typedef __attribute__((ext_vector_type(4))) unsigned int u32x4;
typedef __attribute__((ext_vector_type(2))) unsigned int u32x2;

__device__ __forceinline__ f16x2 bch2(unsigned u) { return __builtin_bit_cast(f16x2, u); }
__device__ __forceinline__ unsigned bcu(f16x2 v) { return __builtin_bit_cast(unsigned, v); }

// ---- kernel 0: x NCHW f32 -> NHWC f16 (xt[b][h][w][c]) via LDS tile transpose
__global__ __launch_bounds__(256) void x_to_nhwc(const float* __restrict__ x,
                                                 _Float16* __restrict__ xt) {
    __shared__ _Float16 tile[W][68];
    int bh = blockIdx.x;
    int h = bh & (H - 1), b = bh >> 7;
    int t = threadIdx.x;
    #pragma unroll
    for (int i = 0; i < 8; ++i) {
        int idx = i * 256 + t;
        int c = idx >> 5;
        int w4 = (idx & 31) << 2;
        f32x4 v = *(const f32x4*)(x + (((size_t)(b * CIN + c) * H + h) * W + w4));
        #pragma unroll
        for (int j = 0; j < 4; ++j) tile[w4 + j][c] = (_Float16)v[j];
    }
    __syncthreads();
    _Float16* dst = xt + (size_t)bh * W * CIN;
    #pragma unroll
    for (int i = 0; i < 8; ++i) {
        int idx = i * 256 + t;
        int w = idx >> 4;
        int c4 = (idx & 15) << 2;
        *(uint2*)(dst + (size_t)w * CIN + c4) = *(const uint2*)&tile[w][c4];
    }
}

// ---- kernel 1: prepack weights, MFMA-lane-coalesced layout
__global__ __launch_bounds__(256) void prep_w(const float* __restrict__ wo,
                                              const float* __restrict__ wc,
                                              _Float16* __restrict__ wao2,
                                              _Float16* __restrict__ wac2) {
    int t = blockIdx.x * 256 + threadIdx.x;
    if (t < 18432) {
        int j = t & 7, l = (t >> 3) & 63, m = (t >> 9) & 1, kk = t >> 10;
        int cout = m * 16 + (l & 15);
        int cin = (kk & 1) * 32 + ((l >> 4) << 3) + j;
        wao2[t] = (cout < 18) ? (_Float16)wo[(cout * 64 + cin) * 9 + (kk >> 1)]
                              : (_Float16)0.f;
    } else if (t < 18432 + 36864) {
        int u = t - 18432;
        int j = u & 7, l = (u >> 3) & 63, m = (u >> 9) & 3, kk = u >> 11;
        int cout = m * 16 + (l & 15);
        int cin = (kk & 1) * 32 + ((l >> 4) << 3) + j;
        wac2[u] = (_Float16)wc[(cout * 64 + cin) * 9 + (kk >> 1)];
    }
}

// ---- kernel 2: fused offset-conv + coord setup + deformable conv.
// Phase C software-pipelined: tap k+1's 8 ds_read_b128 issued before blending
// tap k (double-buffered corner registers).
__global__ __launch_bounds__(256, 4) void deform_fused(const _Float16* __restrict__ xt,
                                                       const _Float16* __restrict__ wao2,
                                                       const _Float16* __restrict__ wac2,
                                                       const float* __restrict__ bo,
                                                       const float* __restrict__ bconv,
                                                       float* __restrict__ out) {
    __shared__ u32x4   s_x[8 * PLANE];   // [chunk c/8][row*CW+col], 16B slots = 20.7 KB
    __shared__ unsigned s_aw[4][9][16];  // s00 | dxb<<9 | dyb<<10 | oow<<11 | a00<<12
    __shared__ u32x2   s_wq[4][9][16];   // {g0,g1},{g2,g3} packed f16

    int bid = blockIdx.x;
    int b = bid & 7;                      // XCD swizzle: XCD k <- batch k
    int r = bid >> 3;
    int h0 = ((r >> 3) & 31) << 2;
    int w0 = (r & 7) << 4;

    int r_lo = max(0, h0 - 2), r_hi = min(H - 1, h0 + 5);
    int c_lo = max(0, w0 - 2), c_hi = min(W - 1, w0 + WC + 1);
    int nr = r_hi - r_lo + 1, nc = c_hi - c_lo + 1;

    int t = threadIdx.x;
    int lane = t & 63, wv = t >> 6;
    int pcol = lane & 15, hq = lane >> 4;
    int h = h0 + wv;
    int wp = w0 + pcol;

    const _Float16* xb = xt + (size_t)b * H * W * CIN;

    // ---------- stage x window into LDS chunk-planes ----------
    {
        int cs = t >> 3, ch = t & 7;
        bool act = t < nc * 8;
        for (int rr = 0; rr < nr; ++rr) {
            if (act) {
                u32x4 v = *(const u32x4*)(xb + (size_t)((r_lo + rr) * W + c_lo + cs) * CIN + (ch << 3));
                s_x[ch * PLANE + rr * CW + cs] = v;
            }
        }
    }
    __syncthreads();

    // ---------- phase A: offset conv via MFMA, x from LDS ----------
    f32x4 ao0 = {}, ao1 = {};
    #pragma unroll
    for (int k = 0; k < 9; ++k) {
        int yy = h + k / 3 - 1;
        int xx = wp + k % 3 - 1;
        bool valid = ((unsigned)yy < (unsigned)H) && ((unsigned)xx < (unsigned)W);
        int yc = min(max(yy, 0), H - 1);
        int xc = min(max(xx, 0), W - 1);
        int s = (yc - r_lo) * CW + (xc - c_lo);
        u32x4 ve = s_x[hq * PLANE + s];
        u32x4 vo = s_x[(4 + hq) * PLANE + s];
        u32x4 z = {};
        if (!valid) { ve = z; vo = z; }
        f16x8 be = __builtin_bit_cast(f16x8, ve);
        f16x8 bod = __builtin_bit_cast(f16x8, vo);
        const _Float16* wb = wao2 + (size_t)(4 * k) * 512 + lane * 8;
        ao0 = __builtin_amdgcn_mfma_f32_16x16x32_f16(*(const f16x8*)(wb), be, ao0, 0, 0, 0);
        ao1 = __builtin_amdgcn_mfma_f32_16x16x32_f16(*(const f16x8*)(wb + 512), be, ao1, 0, 0, 0);
        ao0 = __builtin_amdgcn_mfma_f32_16x16x32_f16(*(const f16x8*)(wb + 1024), bod, ao0, 0, 0, 0);
        ao1 = __builtin_amdgcn_mfma_f32_16x16x32_f16(*(const f16x8*)(wb + 1536), bod, ao1, 0, 0, 0);
    }

    // ---------- per-lane coordinate setup ----------
    auto setup = [&](int k, float dy, float dx) {
        float py = (float)(h + k / 3 - 1) + dy;
        float px = (float)(wp + k % 3 - 1) + dx;
        float y0f = floorf(py), x0f = floorf(px);
        float fy = py - y0f, fx = px - x0f;
        float vy0 = (y0f >= 0.f  && y0f <= 127.f) ? 1.f : 0.f;
        float vy1 = (y0f >= -1.f && y0f <= 126.f) ? 1.f : 0.f;
        float vx0 = (x0f >= 0.f  && x0f <= 127.f) ? 1.f : 0.f;
        float vx1 = (x0f >= -1.f && x0f <= 126.f) ? 1.f : 0.f;
        float g0 = (1.f - fy) * (1.f - fx) * vy0 * vx0;
        float g1 = (1.f - fy) * fx         * vy0 * vx1;
        float g2 = fy * (1.f - fx)         * vy1 * vx0;
        float g3 = fy * fx                 * vy1 * vx1;
        int y0i = (int)fminf(fmaxf(y0f, 0.f), 127.f);
        int x0i = (int)fminf(fmaxf(x0f, 0.f), 127.f);
        int y1i = (int)fminf(fmaxf(y0f + 1.f, 0.f), 127.f);
        int x1i = (int)fminf(fmaxf(x0f + 1.f, 0.f), 127.f);
        unsigned dxb = (unsigned)(x1i - x0i);
        unsigned dyb = (unsigned)(y1i - y0i);
        bool inw = (y0i >= r_lo) && (y1i <= r_hi) && (x0i >= c_lo) && (x1i <= c_hi);
        unsigned s00 = inw ? (unsigned)((y0i - r_lo) * CW + (x0i - c_lo)) : 0u;
        unsigned a00 = (unsigned)(y0i * W + x0i);
        s_aw[wv][k][pcol] = s00 | (dxb << 9) | (dyb << 10) | (inw ? 0u : (1u << 11)) | (a00 << 12);
        u32x2 wq;
        wq[0] = bcu((f16x2){(_Float16)g0, (_Float16)g1});
        wq[1] = bcu((f16x2){(_Float16)g2, (_Float16)g3});
        s_wq[wv][k][pcol] = wq;
    };
    f32x4 bo4 = *(const f32x4*)(bo + 4 * hq);
    setup(2 * hq,     ao0[0] + bo4[0], ao0[1] + bo4[1]);
    setup(2 * hq + 1, ao0[2] + bo4[2], ao0[3] + bo4[3]);
    if (hq == 0) setup(8, ao1[0] + bo[16], ao1[1] + bo[17]);
    __syncthreads();

    // ---------- phase C: deformable conv, 2-deep software pipeline ----------
    const _Float16* xh = xb + (hq << 3);
    const u32x4* se = s_x + hq * PLANE;
    const u32x4* so = s_x + (4 + hq) * PLANE;
    f32x4 acc[4] = {};

    u32x4 Eb[2][4], Ob[2][4];
    {   // prologue: issue tap 0 corner reads
        unsigned aw = s_aw[wv][0][pcol];
        unsigned s00 = aw & 511u;
        unsigned dxb = (aw >> 9) & 1u;
        unsigned dyb = (aw >> 10) & 1u;
        unsigned s01 = s00 + dxb, s10 = s00 + dyb * CW, s11 = s10 + dxb;
        Eb[0][0] = se[s00]; Eb[0][1] = se[s01]; Eb[0][2] = se[s10]; Eb[0][3] = se[s11];
        Ob[0][0] = so[s00]; Ob[0][1] = so[s01]; Ob[0][2] = so[s10]; Ob[0][3] = so[s11];
    }
    #pragma unroll
    for (int k = 0; k < 9; ++k) {
        const int cur = k & 1, nxt = cur ^ 1;
        unsigned aw = s_aw[wv][k][pcol];
        u32x2 wq = s_wq[wv][k][pcol];
        if (k < 8) {   // prefetch tap k+1 corners into the other buffer
            unsigned awn = s_aw[wv][k + 1][pcol];
            unsigned n00 = awn & 511u;
            unsigned ndx = (awn >> 9) & 1u;
            unsigned ndy = (awn >> 10) & 1u;
            unsigned n01 = n00 + ndx, n10 = n00 + ndy * CW, n11 = n10 + ndx;
            Eb[nxt][0] = se[n00]; Eb[nxt][1] = se[n01]; Eb[nxt][2] = se[n10]; Eb[nxt][3] = se[n11];
            Ob[nxt][0] = so[n00]; Ob[nxt][1] = so[n01]; Ob[nxt][2] = so[n10]; Ob[nxt][3] = so[n11];
        }
        u32x4 e00 = Eb[cur][0], e01 = Eb[cur][1], e10 = Eb[cur][2], e11 = Eb[cur][3];
        u32x4 o00 = Ob[cur][0], o01 = Ob[cur][1], o10 = Ob[cur][2], o11 = Ob[cur][3];
        if (__builtin_expect((aw & (1u << 11)) != 0u, 0)) {   // rare far-offset fallback
            unsigned dxb = (aw >> 9) & 1u;
            unsigned dyb = (aw >> 10) & 1u;
            unsigned a00 = aw >> 12;
            unsigned a01 = a00 + dxb;
            unsigned a10 = a00 + (dyb << 7);
            unsigned a11 = a10 + dxb;
            const _Float16* p00 = xh + (size_t)a00 * CIN;
            const _Float16* p01 = xh + (size_t)a01 * CIN;
            const _Float16* p10 = xh + (size_t)a10 * CIN;
            const _Float16* p11 = xh + (size_t)a11 * CIN;
            e00 = *(const u32x4*)p00; o00 = *(const u32x4*)(p00 + 32);
            e01 = *(const u32x4*)p01; o01 = *(const u32x4*)(p01 + 32);
            e10 = *(const u32x4*)p10; o10 = *(const u32x4*)(p10 + 32);
            e11 = *(const u32x4*)p11; o11 = *(const u32x4*)(p11 + 32);
        }
        f16x2 wab = bch2(wq[0]);
        f16x2 wcd = bch2(wq[1]);
        f16x2 w00d = (f16x2){wab[0], wab[0]};
        f16x2 w01d = (f16x2){wab[1], wab[1]};
        f16x2 w10d = (f16x2){wcd[0], wcd[0]};
        f16x2 w11d = (f16x2){wcd[1], wcd[1]};
        u32x4 fe, fo;
        #pragma unroll
        for (int d = 0; d < 4; ++d) {
            f16x2 ve = bch2(e00[d]) * w00d + bch2(e01[d]) * w01d
                     + bch2(e10[d]) * w10d + bch2(e11[d]) * w11d;
            f16x2 vo = bch2(o00[d]) * w00d + bch2(o01[d]) * w01d
                     + bch2(o10[d]) * w10d + bch2(o11[d]) * w11d;
            fe[d] = bcu(ve);
            fo[d] = bcu(vo);
        }
        f16x8 bfe = __builtin_bit_cast(f16x8, fe);
        f16x8 bfo = __builtin_bit_cast(f16x8, fo);
        const _Float16* ab = wac2 + (size_t)(8 * k) * 512 + lane * 8;
        #pragma unroll
        for (int m = 0; m < 4; ++m)
            acc[m] = __builtin_amdgcn_mfma_f32_16x16x32_f16(*(const f16x8*)(ab + m * 512), bfe, acc[m], 0, 0, 0);
        #pragma unroll
        for (int m = 0; m < 4; ++m)
            acc[m] = __builtin_amdgcn_mfma_f32_16x16x32_f16(*(const f16x8*)(ab + (4 + m) * 512), bfo, acc[m], 0, 0, 0);
    }

    #pragma unroll
    for (int m = 0; m < 4; ++m) {
        f32x4 bc4 = *(const f32x4*)(bconv + m * 16 + (hq << 2));
        #pragma unroll
        for (int r2 = 0; r2 < 4; ++r2) {
            int co = (m << 4) + (hq << 2) + r2;
            out[(((size_t)b * COUT + co) * H + h) * W + wp] = acc[m][r2] + bc4[r2];
        }
    }
}

extern "C" void kernel_launch(void* const* d_in, const int* in_sizes, int n_in,
                              void* d_out, int out_size, void* d_ws, size_t ws_size,
                              hipStream_t stream) {
    const float* x  = (const float*)d_in[0];
    const float* wo = (const float*)d_in[1];
    const float* bo = (const float*)d_in[2];
    const float* wc = (const float*)d_in[3];
    const float* bc = (const float*)d_in[4];
    float* out = (float*)d_out;

    _Float16* xt   = (_Float16*)d_ws;                                   // 16.78 MB
    _Float16* wao2 = (_Float16*)((char*)d_ws + (size_t)NB * H * W * CIN * 2);
    _Float16* wac2 = wao2 + 18432;

    x_to_nhwc<<<NB * H, 256, 0, stream>>>(x, xt);
    prep_w<<<(18432 + 36864 + 255) / 256, 256, 0, stream>>>(wo, wc, wao2, wac2);
    deform_fused<<<NB * H * W / (WR * WC), 256, 0, stream>>>(xt, wao2, wac2, bo, bc, out);
}